// Round 6
// baseline (238.022 us; speedup 1.0000x reference)
//
#include <hip/hip_runtime.h>

typedef unsigned short u16;
typedef unsigned int   u32;
typedef __bf16  bf16x8 __attribute__((ext_vector_type(8)));
typedef float   f32x4  __attribute__((ext_vector_type(4)));
typedef u32     u32x4  __attribute__((ext_vector_type(4)));

#define SEQ    2048
#define HEADS  16
#define DM     1024
#define NBH    32      /* B*H */
#define NBS    4096    /* B*S */

// log2(e): flash softmax runs in exp2 domain; folded into Q's RoPE scale.
#define LOG2E  1.4426950408889634f

__device__ __forceinline__ u16 f2b(float f) {
    u32 x;
    __builtin_memcpy(&x, &f, 4);
    return (u16)((x + 0x7fffu + ((x >> 16) & 1u)) >> 16);  // RNE
}

// Native-cast pack: compiler emits v_cvt_pk_bf16_f32 (RNE on gfx950).
__device__ __forceinline__ u32 pkc(float lo, float hi) {
    __bf16 a = (__bf16)lo, b = (__bf16)hi;
    u16 x, y;
    __builtin_memcpy(&x, &a, 2);
    __builtin_memcpy(&y, &b, 2);
    return (u32)x | ((u32)y << 16);
}

__device__ __forceinline__ bf16x8 ld_bf8(const u16* p) {
    return *(const bf16x8*)p;
}

// Async global->LDS, 16 B per lane. LDS dest must be linear (wave-uniform
// base + lane*16); any swizzle goes on the GLOBAL source address (T21).
__device__ __forceinline__ void gl_lds16(const u16* g, __bf16* l) {
    __builtin_amdgcn_global_load_lds(
        (__attribute__((address_space(1))) void*)g,
        (__attribute__((address_space(3))) void*)l,
        16, 0, 0);
}

// ---------------------------------------------------------------------------
// Transpose + fp32->bf16 of W_Q/W_K/W_V: (k,n) -> WqkvT[z*1024 + n][k].
// ---------------------------------------------------------------------------
__global__ __launch_bounds__(256) void transpose_wqkv(const float* __restrict__ Wq,
                                                      const float* __restrict__ Wk,
                                                      const float* __restrict__ Wv,
                                                      u16* __restrict__ WqkvT) {
    __shared__ u16 tile[64][65];
    const int z  = blockIdx.z;
    const float* src = (z == 0) ? Wq : (z == 1) ? Wk : Wv;
    const int k0 = blockIdx.x * 64, n0 = blockIdx.y * 64;
    const int tid = threadIdx.x;
    for (int i = 0; i < 16; ++i) {
        int e = i * 256 + tid;
        int r = e >> 6, c = e & 63;
        tile[r][c] = f2b(src[(size_t)(k0 + r) * DM + n0 + c]);
    }
    __syncthreads();
    u16* dst = WqkvT + (size_t)z * DM * DM;
    for (int i = 0; i < 16; ++i) {
        int e = i * 256 + tid;
        int r = e >> 6, c = e & 63;
        dst[(size_t)(n0 + r) * DM + k0 + c] = tile[c][r];
    }
}

// W_O (k,n) fp32 -> WoT[n][k] bf16. Launched AFTER flash (overlays dead vt).
__global__ __launch_bounds__(256) void transpose_wo(const float* __restrict__ Wo,
                                                    u16* __restrict__ WoT) {
    __shared__ u16 tile[64][65];
    const int k0 = blockIdx.x * 64, n0 = blockIdx.y * 64;
    const int tid = threadIdx.x;
    for (int i = 0; i < 16; ++i) {
        int e = i * 256 + tid;
        int r = e >> 6, c = e & 63;
        tile[r][c] = f2b(Wo[(size_t)(k0 + r) * DM + n0 + c]);
    }
    __syncthreads();
    for (int i = 0; i < 16; ++i) {
        int e = i * 256 + tid;
        int r = e >> 6, c = e & 63;
        WoT[(size_t)(n0 + r) * DM + k0 + c] = tile[c][r];
    }
}

// ---------------------------------------------------------------------------
// x fp32 -> bf16, 8 elems/thread. Output xb lives in the (dead until gemm_wo)
// fp32 output buffer: gemm_wo rewrites every byte of `out` afterwards.
// ---------------------------------------------------------------------------
__global__ __launch_bounds__(256) void cvt_x(const float* __restrict__ x,
                                             u16* __restrict__ xb) {
    int t = blockIdx.x * 256 + threadIdx.x;     // [0, 524288)
    const float* p = x + (size_t)t * 8;
    f32x4 a = *(const f32x4*)p;
    f32x4 b = *(const f32x4*)(p + 4);
    u32x4 v;
    v[0] = pkc(a[0], a[1]);
    v[1] = pkc(a[2], a[3]);
    v[2] = pkc(b[0], b[1]);
    v[3] = pkc(b[2], b[3]);
    *(u32x4*)(xb + (size_t)t * 8) = v;
}

// ---------------------------------------------------------------------------
// Fused QKV GEMM: xb(4096x1024 bf16) x WqkvT(3072x1024 bf16)^T.
// 128x128 tile, BK=64, both operands via global_load_lds (linear dest,
// inverse-swizzled source; XOR-swizzled fragment reads). Zero staging VALU.
// Epilogue scatters to Qp (bh,s,d), Kp (bh,s,d), Vt (bh,d,s).
// ---------------------------------------------------------------------------
__global__ __launch_bounds__(256) void gemm_qkv(const u16* __restrict__ Ab,
                                                const u16* __restrict__ Bt,
                                                u16* __restrict__ Qp,
                                                u16* __restrict__ Kp,
                                                u16* __restrict__ Vt) {
    __shared__ __attribute__((aligned(16))) __bf16 As[128 * 64];
    __shared__ __attribute__((aligned(16))) __bf16 Bs[128 * 64];
    const int tid  = threadIdx.x;
    const int wave = tid >> 6, lane = tid & 63;
    const int quad = lane >> 4, col = lane & 15;
    const int wm = wave >> 1, wn = wave & 1;
    const int m0 = blockIdx.x * 128, n0 = blockIdx.y * 128;
    const int srow = tid >> 3;                  // 0..31
    const int aslot = (((tid & 7) ^ (srow & 7)) << 3);  // swizzled slot (elems)
    const int c7 = col & 7;

    f32x4 zero = {0.f, 0.f, 0.f, 0.f};
    f32x4 acc[4][4];
    for (int i = 0; i < 4; ++i)
        for (int j = 0; j < 4; ++j) acc[i][j] = zero;

    for (int k0 = 0; k0 < DM; k0 += 64) {
        __syncthreads();
#pragma unroll
        for (int p = 0; p < 4; ++p)
            gl_lds16(Ab + (size_t)(m0 + p * 32 + srow) * DM + k0 + aslot,
                     &As[p * 2048 + tid * 8]);
#pragma unroll
        for (int p = 0; p < 4; ++p)
            gl_lds16(Bt + (size_t)(n0 + p * 32 + srow) * DM + k0 + aslot,
                     &Bs[p * 2048 + tid * 8]);
        __syncthreads();
#pragma unroll
        for (int ks = 0; ks < 2; ++ks) {
            const int rsl = ((((ks << 2) | quad) ^ c7) << 3);
            bf16x8 af[4], bfr[4];
#pragma unroll
            for (int mt = 0; mt < 4; ++mt)
                af[mt] = *(const bf16x8*)&As[(wm * 64 + mt * 16 + col) * 64 + rsl];
#pragma unroll
            for (int nt = 0; nt < 4; ++nt)
                bfr[nt] = *(const bf16x8*)&Bs[(wn * 64 + nt * 16 + col) * 64 + rsl];
#pragma unroll
            for (int mt = 0; mt < 4; ++mt)
#pragma unroll
                for (int nt = 0; nt < 4; ++nt)
                    acc[mt][nt] = __builtin_amdgcn_mfma_f32_16x16x32_bf16(
                        af[mt], bfr[nt], acc[mt][nt], 0, 0, 0);
        }
    }

    // C/D: col = lane&15, row = quad*4 + reg (m89-verified).
    for (int mt = 0; mt < 4; ++mt)
        for (int nt = 0; nt < 4; ++nt) {
            int cc = n0 + wn * 64 + nt * 16 + col;       // [0,3072)
            int which = cc >> 10;                        // 0=Q 1=K 2=V
            int c1 = cc & 1023;
            int h = c1 >> 6, d = c1 & 63;
            for (int r = 0; r < 4; ++r) {
                int row = m0 + wm * 64 + mt * 16 + quad * 4 + r;   // [0,4096)
                int b = row >> 11, s = row & (SEQ - 1);
                u16 val = f2b(acc[mt][nt][r]);
                size_t bh = (size_t)(b * HEADS + h);
                if (which == 0)
                    Qp[(bh * SEQ + s) * 64 + d] = val;
                else if (which == 1)
                    Kp[(bh * SEQ + s) * 64 + d] = val;
                else
                    Vt[(bh * 64 + d) * SEQ + s] = val;
            }
        }
}

// ---------------------------------------------------------------------------
// Output GEMM: ao(4096x1024 bf16) x WoT(1024x1024 bf16)^T -> out FP32.
// 128x64 tile -> grid (32,16) = 512 blocks = 2 blocks/CU.
// ---------------------------------------------------------------------------
__global__ __launch_bounds__(256) void gemm_wo(const u16* __restrict__ A,
                                               const u16* __restrict__ Bt,
                                               float* __restrict__ C) {
    __shared__ __attribute__((aligned(16))) __bf16 As[128 * 64];
    __shared__ __attribute__((aligned(16))) __bf16 Bs[64 * 64];
    const int tid  = threadIdx.x;
    const int wave = tid >> 6, lane = tid & 63;
    const int quad = lane >> 4, col = lane & 15;
    const int m0 = blockIdx.x * 128, n0 = blockIdx.y * 64;
    const int srow = tid >> 3;
    const int aslot = (((tid & 7) ^ (srow & 7)) << 3);
    const int c7 = col & 7;

    f32x4 zero = {0.f, 0.f, 0.f, 0.f};
    f32x4 acc[2][4];
    for (int i = 0; i < 2; ++i)
        for (int j = 0; j < 4; ++j) acc[i][j] = zero;

    for (int k0 = 0; k0 < DM; k0 += 64) {
        __syncthreads();
#pragma unroll
        for (int p = 0; p < 4; ++p)
            gl_lds16(A + (size_t)(m0 + p * 32 + srow) * DM + k0 + aslot,
                     &As[p * 2048 + tid * 8]);
#pragma unroll
        for (int p = 0; p < 2; ++p)
            gl_lds16(Bt + (size_t)(n0 + p * 32 + srow) * DM + k0 + aslot,
                     &Bs[p * 2048 + tid * 8]);
        __syncthreads();
#pragma unroll
        for (int ks = 0; ks < 2; ++ks) {
            const int rsl = ((((ks << 2) | quad) ^ c7) << 3);
            bf16x8 af[2], bfr[4];
#pragma unroll
            for (int mt = 0; mt < 2; ++mt)
                af[mt] = *(const bf16x8*)&As[(wave * 32 + mt * 16 + col) * 64 + rsl];
#pragma unroll
            for (int nt = 0; nt < 4; ++nt)
                bfr[nt] = *(const bf16x8*)&Bs[(nt * 16 + col) * 64 + rsl];
#pragma unroll
            for (int mt = 0; mt < 2; ++mt)
#pragma unroll
                for (int nt = 0; nt < 4; ++nt)
                    acc[mt][nt] = __builtin_amdgcn_mfma_f32_16x16x32_bf16(
                        af[mt], bfr[nt], acc[mt][nt], 0, 0, 0);
        }
    }

    for (int mt = 0; mt < 2; ++mt)
        for (int nt = 0; nt < 4; ++nt)
            for (int r = 0; r < 4; ++r) {
                int row = m0 + wave * 32 + mt * 16 + quad * 4 + r;
                int cc  = n0 + nt * 16 + col;
                C[(size_t)row * DM + cc] = acc[mt][nt][r];
            }
}

// ---------------------------------------------------------------------------
// RoPE for Q,K in-place on (bh,s,d) bf16; cos/sin fp32 (S x 32).
// Vectorized 4 pairs/thread. Q gets 0.125*log2(e): flash's softmax runs in
// exp2 domain (scores pre-scaled so v_exp_f32 applies directly, no mul).
// ---------------------------------------------------------------------------
__global__ __launch_bounds__(256) void rope_qk(u16* __restrict__ Qp,
                                               u16* __restrict__ Kp,
                                               const float* __restrict__ cosT,
                                               const float* __restrict__ sinT) {
    int t = blockIdx.x * 256 + threadIdx.x;         // [0, 2^19)
    int g  = t & 7;                                  // pair-group (4 pairs)
    int s  = (t >> 3) & (SEQ - 1);
    int hh = (t >> 14) & (HEADS - 1);
    int b  = t >> 18;

    f32x4 cv = *(const f32x4*)&cosT[s * 32 + g * 4];
    f32x4 sv = *(const f32x4*)&sinT[s * 32 + g * 4];

    const float QS = 0.125f * LOG2E;
    size_t addr = (((size_t)(b * HEADS + hh)) * SEQ + s) * 64 + g * 8;
    u32x4 q4 = *(const u32x4*)(Qp + addr);
    u32x4 k4 = *(const u32x4*)(Kp + addr);
    u32x4 qo4, ko4;
#pragma unroll
    for (int j = 0; j < 4; ++j) {
        u32 q2 = q4[j], k2 = k4[j];
        u32 qe_b = (q2 & 0xffff) << 16, qo_b = q2 & 0xffff0000u;
        u32 ke_b = (k2 & 0xffff) << 16, ko_b = k2 & 0xffff0000u;
        float qe, qo, ke, ko;
        __builtin_memcpy(&qe, &qe_b, 4); __builtin_memcpy(&qo, &qo_b, 4);
        __builtin_memcpy(&ke, &ke_b, 4); __builtin_memcpy(&ko, &ko_b, 4);
        qo4[j] = (u32)f2b(QS * (cv[j] * qe - sv[j] * qo)) |
                 ((u32)f2b(QS * (sv[j] * qe + cv[j] * qo)) << 16);
        ko4[j] = (u32)f2b(cv[j] * ke - sv[j] * ko) |
                 ((u32)f2b(sv[j] * ke + cv[j] * ko) << 16);
    }
    *(u32x4*)(Qp + addr) = qo4;
    *(u32x4*)(Kp + addr) = ko4;
}

// ---------------------------------------------------------------------------
// Causal flash attention R6: ONE WAVE PER WORKGROUP, fully independent.
//
// R5 post-mortem: VALU work is only ~25 us; the other ~55 us is stall at
// 2.4 waves/SIMD residency. The 35.8 KB LDS merge capped blocks/CU at 4 and
// the barrier coupled 4 waves' lifetimes — both exist only to serve split-K.
// Fix: 64-thread WGs, one wave owns one 32-query dual-half tile and sweeps
// its full causal key range. Zero LDS, zero barriers, waves retire
// independently, heavy-first + XCD-pinned. 2048 single-wave WGs.
//
// K/V prefetched one tile ahead, unclamped (reads stay inside the 32 MiB
// workspace; garbage is never consumed) -> affine addresses, no clamp logic.
// Exp2-domain softmax, defer-max, shuffle-butterfly P-transpose (all
// R0/R3/R5-verified pieces).
// Qp,Kp: (bh,s,64)  Vt: (bh,64,s)  O: (b, s, h*64+d) bf16.
// ---------------------------------------------------------------------------
__global__ __launch_bounds__(64) void flash_attn(const u16* __restrict__ Qp,
                                                 const u16* __restrict__ Kp,
                                                 const u16* __restrict__ Vt,
                                                 u16* __restrict__ O) {
    const int lane = threadIdx.x;              // 0..63
    const int quad = lane >> 4, col = lane & 15;
    const bool hi5 = lane >= 32;
    const bool hi4 = (lane & 16) != 0;
    const int bh = blockIdx.x;                 // XCD-pinned: lin%8 == bh%8
    const int b = bh >> 4, h = bh & 15;
    const int qt = 63 - blockIdx.y;            // heavy tiles first
    const int q0 = qt * 32;

    const u16* Qb = Qp + (size_t)bh * SEQ * 64;
    const u16* Kb = Kp + (size_t)bh * SEQ * 64;
    const u16* Vb = Vt + (size_t)bh * 64 * SEQ;

    // Q as B-operand for both halves (n=col -> query, k=quad*8+j)
    bf16x8 bq00 = ld_bf8(Qb + (size_t)(q0 + col) * 64 + quad * 8);
    bf16x8 bq01 = ld_bf8(Qb + (size_t)(q0 + col) * 64 + 32 + quad * 8);
    bf16x8 bq10 = ld_bf8(Qb + (size_t)(q0 + 16 + col) * 64 + quad * 8);
    bf16x8 bq11 = ld_bf8(Qb + (size_t)(q0 + 16 + col) * 64 + 32 + quad * 8);

    f32x4 zero = {0.f, 0.f, 0.f, 0.f};
    f32x4 o0[4] = {zero, zero, zero, zero};
    f32x4 o1[4] = {zero, zero, zero, zero};
    float m0_ = -1e30f, m1_ = -1e30f;
    float lp0 = 0.f, lp1 = 0.f;                // per-lane l partials

    const int nkt = qt + 1;                    // 32-key tiles (causal)

    // current K/V (tile 0)
    bf16x8 ck00 = ld_bf8(Kb + (size_t)col * 64 + quad * 8);
    bf16x8 ck01 = ld_bf8(Kb + (size_t)col * 64 + 32 + quad * 8);
    bf16x8 ck10 = ld_bf8(Kb + (size_t)(16 + col) * 64 + quad * 8);
    bf16x8 ck11 = ld_bf8(Kb + (size_t)(16 + col) * 64 + 32 + quad * 8);
    bf16x8 cv0  = ld_bf8(Vb + (size_t)(0 * 16 + col) * SEQ + quad * 8);
    bf16x8 cv1  = ld_bf8(Vb + (size_t)(1 * 16 + col) * SEQ + quad * 8);
    bf16x8 cv2  = ld_bf8(Vb + (size_t)(2 * 16 + col) * SEQ + quad * 8);
    bf16x8 cv3  = ld_bf8(Vb + (size_t)(3 * 16 + col) * SEQ + quad * 8);

    for (int kt = 0; kt < nkt; ++kt) {
        const int kb = kt << 5;
        const int kb2 = kb + 32;               // unclamped: in-workspace reads
        bf16x8 nk00 = ld_bf8(Kb + (size_t)(kb2 + col) * 64 + quad * 8);
        bf16x8 nk01 = ld_bf8(Kb + (size_t)(kb2 + col) * 64 + 32 + quad * 8);
        bf16x8 nk10 = ld_bf8(Kb + (size_t)(kb2 + 16 + col) * 64 + quad * 8);
        bf16x8 nk11 = ld_bf8(Kb + (size_t)(kb2 + 16 + col) * 64 + 32 + quad * 8);
        bf16x8 nv0  = ld_bf8(Vb + (size_t)(0 * 16 + col) * SEQ + kb2 + quad * 8);
        bf16x8 nv1  = ld_bf8(Vb + (size_t)(1 * 16 + col) * SEQ + kb2 + quad * 8);
        bf16x8 nv2  = ld_bf8(Vb + (size_t)(2 * 16 + col) * SEQ + kb2 + quad * 8);
        bf16x8 nv3  = ld_bf8(Vb + (size_t)(3 * 16 + col) * SEQ + kb2 + quad * 8);

        // S^T (log2-domain): two independent chains, 8 MFMA
        f32x4 s00 = zero, s01 = zero, s10 = zero, s11 = zero;
        s00 = __builtin_amdgcn_mfma_f32_16x16x32_bf16(ck00, bq00, s00, 0, 0, 0);
        s10 = __builtin_amdgcn_mfma_f32_16x16x32_bf16(ck00, bq10, s10, 0, 0, 0);
        s00 = __builtin_amdgcn_mfma_f32_16x16x32_bf16(ck01, bq01, s00, 0, 0, 0);
        s10 = __builtin_amdgcn_mfma_f32_16x16x32_bf16(ck01, bq11, s10, 0, 0, 0);
        s01 = __builtin_amdgcn_mfma_f32_16x16x32_bf16(ck10, bq00, s01, 0, 0, 0);
        s11 = __builtin_amdgcn_mfma_f32_16x16x32_bf16(ck10, bq10, s11, 0, 0, 0);
        s01 = __builtin_amdgcn_mfma_f32_16x16x32_bf16(ck11, bq01, s01, 0, 0, 0);
        s11 = __builtin_amdgcn_mfma_f32_16x16x32_bf16(ck11, bq11, s11, 0, 0, 0);

        float v00[4], v01[4], v10[4], v11[4];
        float lm0 = -1e30f, lm1 = -1e30f;
        if (kt == qt) {                         // diagonal tile (wave-uniform)
            for (int r = 0; r < 4; ++r) {
                int krel = quad * 4 + r;
                float a0 = (krel > col) ? -1e30f : s00[r];
                float b0 = -1e30f;              // keys+16 > all half0 queries
                float a1 = s10[r];
                float b1 = (krel > col) ? -1e30f : s11[r];
                v00[r] = a0; v01[r] = b0; v10[r] = a1; v11[r] = b1;
                lm0 = fmaxf(lm0, fmaxf(a0, b0));
                lm1 = fmaxf(lm1, fmaxf(a1, b1));
            }
        } else {
            for (int r = 0; r < 4; ++r) {
                v00[r] = s00[r]; v01[r] = s01[r];
                v10[r] = s10[r]; v11[r] = s11[r];
                lm0 = fmaxf(lm0, fmaxf(v00[r], v01[r]));
                lm1 = fmaxf(lm1, fmaxf(v10[r], v11[r]));
            }
        }

        // Defer-max (log2 domain: 8*log2e = 11.54)
        float dd = fmaxf(lm0 - m0_, lm1 - m1_);
        if (__any(dd > 11.54f)) {
            float lr0 = fmaxf(lm0, __shfl_xor(lm0, 16));
            lr0 = fmaxf(lr0, __shfl_xor(lr0, 32));
            float lr1 = fmaxf(lm1, __shfl_xor(lm1, 16));
            lr1 = fmaxf(lr1, __shfl_xor(lr1, 32));
            float mn0 = fmaxf(m0_, lr0), mn1 = fmaxf(m1_, lr1);
            float al0 = __builtin_amdgcn_exp2f(m0_ - mn0);
            float al1 = __builtin_amdgcn_exp2f(m1_ - mn1);
            m0_ = mn0; m1_ = mn1;
            lp0 *= al0; lp1 *= al1;
            for (int r = 0; r < 4; ++r) {
                float ar0 = __shfl(al0, quad * 4 + r);
                float ar1 = __shfl(al1, quad * 4 + r);
                for (int nt = 0; nt < 4; ++nt) {
                    o0[nt][r] *= ar0;
                    o1[nt][r] *= ar1;
                }
            }
        }

        for (int r = 0; r < 4; ++r) {
            v00[r] = __builtin_amdgcn_exp2f(v00[r] - m0_);
            v01[r] = __builtin_amdgcn_exp2f(v01[r] - m0_);
            v10[r] = __builtin_amdgcn_exp2f(v10[r] - m1_);
            v11[r] = __builtin_amdgcn_exp2f(v11[r] - m1_);
            lp0 += v00[r] + v01[r];
            lp1 += v10[r] + v11[r];
        }

        // P^T(C-layout) -> A-fragment: 2-stage shuffle butterfly, per half.
        u32 fwa0[4], fwa1[4];
        {
            u32 A0 = pkc(v00[0], v00[1]), A1 = pkc(v00[2], v00[3]);
            u32 B0 = pkc(v01[0], v01[1]), B1 = pkc(v01[2], v01[3]);
            u32 g0 = hi5 ? A0 : B0,  g1 = hi5 ? A1 : B1;
            u32 r0 = __shfl_xor(g0, 32), r1 = __shfl_xor(g1, 32);
            u32 P00 = hi5 ? r0 : A0,  P01 = hi5 ? r1 : A1;
            u32 P10 = hi5 ? B0 : r0,  P11 = hi5 ? B1 : r1;
            u32 h0 = hi4 ? P00 : P10, h1 = hi4 ? P01 : P11;
            u32 u0 = __shfl_xor(h0, 16), u1 = __shfl_xor(h1, 16);
            fwa0[0] = hi4 ? u0 : P00;  fwa0[1] = hi4 ? u1 : P01;
            fwa0[2] = hi4 ? P10 : u0;  fwa0[3] = hi4 ? P11 : u1;
        }
        {
            u32 A0 = pkc(v10[0], v10[1]), A1 = pkc(v10[2], v10[3]);
            u32 B0 = pkc(v11[0], v11[1]), B1 = pkc(v11[2], v11[3]);
            u32 g0 = hi5 ? A0 : B0,  g1 = hi5 ? A1 : B1;
            u32 r0 = __shfl_xor(g0, 32), r1 = __shfl_xor(g1, 32);
            u32 P00 = hi5 ? r0 : A0,  P01 = hi5 ? r1 : A1;
            u32 P10 = hi5 ? B0 : r0,  P11 = hi5 ? B1 : r1;
            u32 h0 = hi4 ? P00 : P10, h1 = hi4 ? P01 : P11;
            u32 u0 = __shfl_xor(h0, 16), u1 = __shfl_xor(h1, 16);
            fwa1[0] = hi4 ? u0 : P00;  fwa1[1] = hi4 ? u1 : P01;
            fwa1[2] = hi4 ? P10 : u0;  fwa1[3] = hi4 ? P11 : u1;
        }
        bf16x8 pf0, pf1;
        __builtin_memcpy(&pf0, fwa0, 16);
        __builtin_memcpy(&pf1, fwa1, 16);

        // PV: 8 MFMA, independent across halves and nt
        o0[0] = __builtin_amdgcn_mfma_f32_16x16x32_bf16(pf0, cv0, o0[0], 0, 0, 0);
        o1[0] = __builtin_amdgcn_mfma_f32_16x16x32_bf16(pf1, cv0, o1[0], 0, 0, 0);
        o0[1] = __builtin_amdgcn_mfma_f32_16x16x32_bf16(pf0, cv1, o0[1], 0, 0, 0);
        o1[1] = __builtin_amdgcn_mfma_f32_16x16x32_bf16(pf1, cv1, o1[1], 0, 0, 0);
        o0[2] = __builtin_amdgcn_mfma_f32_16x16x32_bf16(pf0, cv2, o0[2], 0, 0, 0);
        o1[2] = __builtin_amdgcn_mfma_f32_16x16x32_bf16(pf1, cv2, o1[2], 0, 0, 0);
        o0[3] = __builtin_amdgcn_mfma_f32_16x16x32_bf16(pf0, cv3, o0[3], 0, 0, 0);
        o1[3] = __builtin_amdgcn_mfma_f32_16x16x32_bf16(pf1, cv3, o1[3], 0, 0, 0);

        ck00 = nk00; ck01 = nk01; ck10 = nk10; ck11 = nk11;
        cv0 = nv0; cv1 = nv1; cv2 = nv2; cv3 = nv3;
    }

    // ---- epilogue: reduce l, normalize, write O (no merge needed)
    float lt0 = lp0;
    lt0 += __shfl_xor(lt0, 16); lt0 += __shfl_xor(lt0, 32);
    float lt1 = lp1;
    lt1 += __shfl_xor(lt1, 16); lt1 += __shfl_xor(lt1, 32);
    float linv0 = 1.f / lt0;
    float linv1 = 1.f / lt1;
    for (int r = 0; r < 4; ++r) {
        float l0r = __shfl(linv0, quad * 4 + r);
        float l1r = __shfl(linv1, quad * 4 + r);
        int qrA = q0 + quad * 4 + r;
        int qrB = qrA + 16;
        for (int nt = 0; nt < 4; ++nt) {
            O[((size_t)b * SEQ + qrA) * DM + h * 64 + nt * 16 + col] =
                f2b(o0[nt][r] * l0r);
            O[((size_t)b * SEQ + qrB) * DM + h * 64 + nt * 16 + col] =
                f2b(o1[nt][r] * l1r);
        }
    }
}

// ---------------------------------------------------------------------------
extern "C" void kernel_launch(void* const* d_in, const int* in_sizes, int n_in,
                              void* d_out, int out_size, void* d_ws, size_t ws_size,
                              hipStream_t stream) {
    const float* x    = (const float*)d_in[0];   // fp32 inputs (R3->R5 proven)
    const float* Wq   = (const float*)d_in[2];
    const float* Wk   = (const float*)d_in[3];
    const float* Wv   = (const float*)d_in[4];
    const float* Wo   = (const float*)d_in[5];
    const float* cosT = (const float*)d_in[6];
    const float* sinT = (const float*)d_in[7];
    float* out = (float*)d_out;                  // fp32 output (R8 proven)

    // Workspace: 16,777,216 u16 = 32 MiB (R8-proven safe size).
    u16* ws    = (u16*)d_ws;
    u16* qp    = ws;               // (bh,s,d)
    u16* kp    = ws + 4194304;
    u16* vt    = ws + 8388608;     // (bh,d,s); dead after flash
    u16* woT   = ws + 8388608;     // overlays vt, written after flash
    u16* wqkvT = ws + 12582912;    // dead after gemm_qkv
    u16* ao    = ws + 12582912;    // overlays wqkvT
    // bf16 copy of x lives in the OUTPUT buffer (8 of its 16 MiB): out is
    // dead until gemm_wo, which rewrites every element afterwards.
    u16* xb    = (u16*)out;

    dim3 blk(256);
    transpose_wqkv<<<dim3(16, 16, 3), blk, 0, stream>>>(Wq, Wk, Wv, wqkvT);
    cvt_x<<<dim3(2048), blk, 0, stream>>>(x, xb);
    gemm_qkv<<<dim3(32, 24), blk, 0, stream>>>(xb, wqkvT, qp, kp, vt);
    rope_qk<<<dim3(2048), blk, 0, stream>>>(qp, kp, cosT, sinT);
    flash_attn<<<dim3(NBH, 64), dim3(64), 0, stream>>>(qp, kp, vt, ao);
    transpose_wo<<<dim3(16, 16), blk, 0, stream>>>(Wo, woT);
    gemm_wo<<<dim3(32, 16), blk, 0, stream>>>(ao, woT, out);
}

// Round 7
// 233.639 us; speedup vs baseline: 1.0188x; 1.0188x over previous
//
#include <hip/hip_runtime.h>

typedef unsigned short u16;
typedef unsigned int   u32;
typedef __bf16  bf16x8 __attribute__((ext_vector_type(8)));
typedef float   f32x4  __attribute__((ext_vector_type(4)));
typedef u32     u32x4  __attribute__((ext_vector_type(4)));

#define SEQ    2048
#define HEADS  16
#define DM     1024
#define NBH    32      /* B*H */
#define NBS    4096    /* B*S */

// log2(e): flash softmax runs in exp2 domain; folded into Q's RoPE scale.
#define LOG2E  1.4426950408889634f

__device__ __forceinline__ u16 f2b(float f) {
    u32 x;
    __builtin_memcpy(&x, &f, 4);
    return (u16)((x + 0x7fffu + ((x >> 16) & 1u)) >> 16);  // RNE
}

// Native-cast pack: compiler emits v_cvt_pk_bf16_f32 (RNE on gfx950).
__device__ __forceinline__ u32 pkc(float lo, float hi) {
    __bf16 a = (__bf16)lo, b = (__bf16)hi;
    u16 x, y;
    __builtin_memcpy(&x, &a, 2);
    __builtin_memcpy(&y, &b, 2);
    return (u32)x | ((u32)y << 16);
}

__device__ __forceinline__ bf16x8 ld_bf8(const u16* p) {
    return *(const bf16x8*)p;
}

// Async global->LDS, 16 B per lane. LDS dest must be linear (wave-uniform
// base + lane*16); any swizzle goes on the GLOBAL source address (T21).
__device__ __forceinline__ void gl_lds16(const u16* g, __bf16* l) {
    __builtin_amdgcn_global_load_lds(
        (__attribute__((address_space(1))) void*)g,
        (__attribute__((address_space(3))) void*)l,
        16, 0, 0);
}

// ---------------------------------------------------------------------------
// Transpose + fp32->bf16 of W_Q/W_K/W_V: (k,n) -> WqkvT[z*1024 + n][k].
// ---------------------------------------------------------------------------
__global__ __launch_bounds__(256) void transpose_wqkv(const float* __restrict__ Wq,
                                                      const float* __restrict__ Wk,
                                                      const float* __restrict__ Wv,
                                                      u16* __restrict__ WqkvT) {
    __shared__ u16 tile[64][65];
    const int z  = blockIdx.z;
    const float* src = (z == 0) ? Wq : (z == 1) ? Wk : Wv;
    const int k0 = blockIdx.x * 64, n0 = blockIdx.y * 64;
    const int tid = threadIdx.x;
    for (int i = 0; i < 16; ++i) {
        int e = i * 256 + tid;
        int r = e >> 6, c = e & 63;
        tile[r][c] = f2b(src[(size_t)(k0 + r) * DM + n0 + c]);
    }
    __syncthreads();
    u16* dst = WqkvT + (size_t)z * DM * DM;
    for (int i = 0; i < 16; ++i) {
        int e = i * 256 + tid;
        int r = e >> 6, c = e & 63;
        dst[(size_t)(n0 + r) * DM + k0 + c] = tile[c][r];
    }
}

// W_O (k,n) fp32 -> WoT[n][k] bf16. Launched AFTER flash (overlays dead vt).
__global__ __launch_bounds__(256) void transpose_wo(const float* __restrict__ Wo,
                                                    u16* __restrict__ WoT) {
    __shared__ u16 tile[64][65];
    const int k0 = blockIdx.x * 64, n0 = blockIdx.y * 64;
    const int tid = threadIdx.x;
    for (int i = 0; i < 16; ++i) {
        int e = i * 256 + tid;
        int r = e >> 6, c = e & 63;
        tile[r][c] = f2b(Wo[(size_t)(k0 + r) * DM + n0 + c]);
    }
    __syncthreads();
    for (int i = 0; i < 16; ++i) {
        int e = i * 256 + tid;
        int r = e >> 6, c = e & 63;
        WoT[(size_t)(n0 + r) * DM + k0 + c] = tile[c][r];
    }
}

// ---------------------------------------------------------------------------
// x fp32 -> bf16, 8 elems/thread. Output xb lives in the (dead until gemm_wo)
// fp32 output buffer: gemm_wo rewrites every byte of `out` afterwards.
// ---------------------------------------------------------------------------
__global__ __launch_bounds__(256) void cvt_x(const float* __restrict__ x,
                                             u16* __restrict__ xb) {
    int t = blockIdx.x * 256 + threadIdx.x;     // [0, 524288)
    const float* p = x + (size_t)t * 8;
    f32x4 a = *(const f32x4*)p;
    f32x4 b = *(const f32x4*)(p + 4);
    u32x4 v;
    v[0] = pkc(a[0], a[1]);
    v[1] = pkc(a[2], a[3]);
    v[2] = pkc(b[0], b[1]);
    v[3] = pkc(b[2], b[3]);
    *(u32x4*)(xb + (size_t)t * 8) = v;
}

// ---------------------------------------------------------------------------
// Fused QKV GEMM: xb(4096x1024 bf16) x WqkvT(3072x1024 bf16)^T.
// 128x128 tile, BK=64, both operands via global_load_lds (linear dest,
// inverse-swizzled source; XOR-swizzled fragment reads). Zero staging VALU.
// Epilogue scatters to Qp (bh,s,d), Kp (bh,s,d), Vt (bh,d,s).
// ---------------------------------------------------------------------------
__global__ __launch_bounds__(256) void gemm_qkv(const u16* __restrict__ Ab,
                                                const u16* __restrict__ Bt,
                                                u16* __restrict__ Qp,
                                                u16* __restrict__ Kp,
                                                u16* __restrict__ Vt) {
    __shared__ __attribute__((aligned(16))) __bf16 As[128 * 64];
    __shared__ __attribute__((aligned(16))) __bf16 Bs[128 * 64];
    const int tid  = threadIdx.x;
    const int wave = tid >> 6, lane = tid & 63;
    const int quad = lane >> 4, col = lane & 15;
    const int wm = wave >> 1, wn = wave & 1;
    const int m0 = blockIdx.x * 128, n0 = blockIdx.y * 128;
    const int srow = tid >> 3;                  // 0..31
    const int aslot = (((tid & 7) ^ (srow & 7)) << 3);  // swizzled slot (elems)
    const int c7 = col & 7;

    f32x4 zero = {0.f, 0.f, 0.f, 0.f};
    f32x4 acc[4][4];
    for (int i = 0; i < 4; ++i)
        for (int j = 0; j < 4; ++j) acc[i][j] = zero;

    for (int k0 = 0; k0 < DM; k0 += 64) {
        __syncthreads();
#pragma unroll
        for (int p = 0; p < 4; ++p)
            gl_lds16(Ab + (size_t)(m0 + p * 32 + srow) * DM + k0 + aslot,
                     &As[p * 2048 + tid * 8]);
#pragma unroll
        for (int p = 0; p < 4; ++p)
            gl_lds16(Bt + (size_t)(n0 + p * 32 + srow) * DM + k0 + aslot,
                     &Bs[p * 2048 + tid * 8]);
        __syncthreads();
#pragma unroll
        for (int ks = 0; ks < 2; ++ks) {
            const int rsl = ((((ks << 2) | quad) ^ c7) << 3);
            bf16x8 af[4], bfr[4];
#pragma unroll
            for (int mt = 0; mt < 4; ++mt)
                af[mt] = *(const bf16x8*)&As[(wm * 64 + mt * 16 + col) * 64 + rsl];
#pragma unroll
            for (int nt = 0; nt < 4; ++nt)
                bfr[nt] = *(const bf16x8*)&Bs[(wn * 64 + nt * 16 + col) * 64 + rsl];
#pragma unroll
            for (int mt = 0; mt < 4; ++mt)
#pragma unroll
                for (int nt = 0; nt < 4; ++nt)
                    acc[mt][nt] = __builtin_amdgcn_mfma_f32_16x16x32_bf16(
                        af[mt], bfr[nt], acc[mt][nt], 0, 0, 0);
        }
    }

    // C/D: col = lane&15, row = quad*4 + reg (m89-verified).
    for (int mt = 0; mt < 4; ++mt)
        for (int nt = 0; nt < 4; ++nt) {
            int cc = n0 + wn * 64 + nt * 16 + col;       // [0,3072)
            int which = cc >> 10;                        // 0=Q 1=K 2=V
            int c1 = cc & 1023;
            int h = c1 >> 6, d = c1 & 63;
            for (int r = 0; r < 4; ++r) {
                int row = m0 + wm * 64 + mt * 16 + quad * 4 + r;   // [0,4096)
                int b = row >> 11, s = row & (SEQ - 1);
                u16 val = f2b(acc[mt][nt][r]);
                size_t bh = (size_t)(b * HEADS + h);
                if (which == 0)
                    Qp[(bh * SEQ + s) * 64 + d] = val;
                else if (which == 1)
                    Kp[(bh * SEQ + s) * 64 + d] = val;
                else
                    Vt[(bh * 64 + d) * SEQ + s] = val;
            }
        }
}

// ---------------------------------------------------------------------------
// Output GEMM: ao(4096x1024 bf16) x WoT(1024x1024 bf16)^T -> out FP32.
// 128x64 tile -> grid (32,16) = 512 blocks = 2 blocks/CU.
// ---------------------------------------------------------------------------
__global__ __launch_bounds__(256) void gemm_wo(const u16* __restrict__ A,
                                               const u16* __restrict__ Bt,
                                               float* __restrict__ C) {
    __shared__ __attribute__((aligned(16))) __bf16 As[128 * 64];
    __shared__ __attribute__((aligned(16))) __bf16 Bs[64 * 64];
    const int tid  = threadIdx.x;
    const int wave = tid >> 6, lane = tid & 63;
    const int quad = lane >> 4, col = lane & 15;
    const int m0 = blockIdx.x * 128, n0 = blockIdx.y * 64;
    const int srow = tid >> 3;
    const int aslot = (((tid & 7) ^ (srow & 7)) << 3);
    const int c7 = col & 7;

    f32x4 zero = {0.f, 0.f, 0.f, 0.f};
    f32x4 acc[2][4];
    for (int i = 0; i < 2; ++i)
        for (int j = 0; j < 4; ++j) acc[i][j] = zero;

    for (int k0 = 0; k0 < DM; k0 += 64) {
        __syncthreads();
#pragma unroll
        for (int p = 0; p < 4; ++p)
            gl_lds16(A + (size_t)(m0 + p * 32 + srow) * DM + k0 + aslot,
                     &As[p * 2048 + tid * 8]);
#pragma unroll
        for (int p = 0; p < 2; ++p)
            gl_lds16(Bt + (size_t)(n0 + p * 32 + srow) * DM + k0 + aslot,
                     &Bs[p * 2048 + tid * 8]);
        __syncthreads();
#pragma unroll
        for (int ks = 0; ks < 2; ++ks) {
            const int rsl = ((((ks << 2) | quad) ^ c7) << 3);
            bf16x8 af[2], bfr[4];
#pragma unroll
            for (int mt = 0; mt < 2; ++mt)
                af[mt] = *(const bf16x8*)&As[(wave * 32 + mt * 16 + col) * 64 + rsl];
#pragma unroll
            for (int nt = 0; nt < 4; ++nt)
                bfr[nt] = *(const bf16x8*)&Bs[(nt * 16 + col) * 64 + rsl];
#pragma unroll
            for (int mt = 0; mt < 2; ++mt)
#pragma unroll
                for (int nt = 0; nt < 4; ++nt)
                    acc[mt][nt] = __builtin_amdgcn_mfma_f32_16x16x32_bf16(
                        af[mt], bfr[nt], acc[mt][nt], 0, 0, 0);
        }
    }

    for (int mt = 0; mt < 2; ++mt)
        for (int nt = 0; nt < 4; ++nt)
            for (int r = 0; r < 4; ++r) {
                int row = m0 + wave * 32 + mt * 16 + quad * 4 + r;
                int cc  = n0 + nt * 16 + col;
                C[(size_t)row * DM + cc] = acc[mt][nt][r];
            }
}

// ---------------------------------------------------------------------------
// RoPE for Q,K in-place on (bh,s,d) bf16; cos/sin fp32 (S x 32).
// Vectorized 4 pairs/thread. Q gets 0.125*log2(e): flash's softmax runs in
// exp2 domain (scores pre-scaled so v_exp_f32 applies directly, no mul).
// ---------------------------------------------------------------------------
__global__ __launch_bounds__(256) void rope_qk(u16* __restrict__ Qp,
                                               u16* __restrict__ Kp,
                                               const float* __restrict__ cosT,
                                               const float* __restrict__ sinT) {
    int t = blockIdx.x * 256 + threadIdx.x;         // [0, 2^19)
    int g  = t & 7;                                  // pair-group (4 pairs)
    int s  = (t >> 3) & (SEQ - 1);
    int hh = (t >> 14) & (HEADS - 1);
    int b  = t >> 18;

    f32x4 cv = *(const f32x4*)&cosT[s * 32 + g * 4];
    f32x4 sv = *(const f32x4*)&sinT[s * 32 + g * 4];

    const float QS = 0.125f * LOG2E;
    size_t addr = (((size_t)(b * HEADS + hh)) * SEQ + s) * 64 + g * 8;
    u32x4 q4 = *(const u32x4*)(Qp + addr);
    u32x4 k4 = *(const u32x4*)(Kp + addr);
    u32x4 qo4, ko4;
#pragma unroll
    for (int j = 0; j < 4; ++j) {
        u32 q2 = q4[j], k2 = k4[j];
        u32 qe_b = (q2 & 0xffff) << 16, qo_b = q2 & 0xffff0000u;
        u32 ke_b = (k2 & 0xffff) << 16, ko_b = k2 & 0xffff0000u;
        float qe, qo, ke, ko;
        __builtin_memcpy(&qe, &qe_b, 4); __builtin_memcpy(&qo, &qo_b, 4);
        __builtin_memcpy(&ke, &ke_b, 4); __builtin_memcpy(&ko, &ko_b, 4);
        qo4[j] = (u32)f2b(QS * (cv[j] * qe - sv[j] * qo)) |
                 ((u32)f2b(QS * (sv[j] * qe + cv[j] * qo)) << 16);
        ko4[j] = (u32)f2b(cv[j] * ke - sv[j] * ko) |
                 ((u32)f2b(sv[j] * ke + cv[j] * ko) << 16);
    }
    *(u32x4*)(Qp + addr) = qo4;
    *(u32x4*)(Kp + addr) = ko4;
}

// ---------------------------------------------------------------------------
// Causal flash attention R7: TWO-WAVE split-K per 32-query tile.
//
// R6 post-mortem: single-wave WGs HALVED residency (8 waves/CU, 12.7% occ)
// and the kernel duration equals the heaviest wave's 64-iteration serial
// chain (~3100 cyc/iter). Fixes:
//  - 2 waves/WG, wave w handles key-tiles kt = w, w+2, ... -> heaviest
//    serial chain 32 iterations; 4096 waves = 16/CU demanded (LDS only 9KB).
//  - Software-pipelined unrolled-2 loop with two register sets: no
//    per-iteration register copies; each load covered by one tile's compute.
//  - Wave-uniform tile index -> loads are saddr + fixed voffset (SALU walk),
//    killing the per-load 64-bit VALU address chains.
//  - Single-sided merge: wave 1 publishes (m,l,o) to LDS, one barrier,
//    wave 0 merges in-register and writes O.
// K/V prefetch reads may run past the tile range; they stay inside the
// 32 MiB workspace and garbage is never consumed.
// Qp,Kp: (bh,s,64)  Vt: (bh,64,s)  O: (b, s, h*64+d) bf16.
// ---------------------------------------------------------------------------
#define FA_MFMA(A, B, C) __builtin_amdgcn_mfma_f32_16x16x32_bf16(A, B, C, 0, 0, 0)

#define FA_LD(K00, K01, K10, K11, V0, V1, V2, V3, T) do {                      \
    size_t kk_ = (size_t)(T) * 2048;                                           \
    size_t vv_ = (size_t)(T) * 32;                                             \
    K00 = ld_bf8(Kb + kk_ + koff);                                             \
    K01 = ld_bf8(Kb + kk_ + koff + 32);                                        \
    K10 = ld_bf8(Kb + kk_ + koff + 1024);                                      \
    K11 = ld_bf8(Kb + kk_ + koff + 1056);                                      \
    V0  = ld_bf8(Vb + vv_ + voff);                                             \
    V1  = ld_bf8(Vb + vv_ + voff + 16 * SEQ);                                  \
    V2  = ld_bf8(Vb + vv_ + voff + 32 * SEQ);                                  \
    V3  = ld_bf8(Vb + vv_ + voff + 48 * SEQ);                                  \
} while (0)

#define FA_TILE(K00, K01, K10, K11, V0, V1, V2, V3, KT) do {                   \
    f32x4 s00 = zero, s01 = zero, s10 = zero, s11 = zero;                      \
    s00 = FA_MFMA(K00, bq00, s00);  s10 = FA_MFMA(K00, bq10, s10);             \
    s00 = FA_MFMA(K01, bq01, s00);  s10 = FA_MFMA(K01, bq11, s10);             \
    s01 = FA_MFMA(K10, bq00, s01);  s11 = FA_MFMA(K10, bq10, s11);             \
    s01 = FA_MFMA(K11, bq01, s01);  s11 = FA_MFMA(K11, bq11, s11);             \
    float v00[4], v01[4], v10[4], v11[4];                                      \
    float lm0 = -1e30f, lm1 = -1e30f;                                          \
    if ((KT) == qt) {                       /* diagonal tile (wave-uniform) */ \
        for (int r = 0; r < 4; ++r) {                                          \
            int krel = quad * 4 + r;                                           \
            float a0 = (krel > col) ? -1e30f : s00[r];                         \
            float b0 = -1e30f;                                                 \
            float a1 = s10[r];                                                 \
            float b1 = (krel > col) ? -1e30f : s11[r];                         \
            v00[r] = a0; v01[r] = b0; v10[r] = a1; v11[r] = b1;                \
            lm0 = fmaxf(lm0, fmaxf(a0, b0));                                   \
            lm1 = fmaxf(lm1, fmaxf(a1, b1));                                   \
        }                                                                      \
    } else {                                                                   \
        for (int r = 0; r < 4; ++r) {                                          \
            v00[r] = s00[r]; v01[r] = s01[r];                                  \
            v10[r] = s10[r]; v11[r] = s11[r];                                  \
            lm0 = fmaxf(lm0, fmaxf(v00[r], v01[r]));                           \
            lm1 = fmaxf(lm1, fmaxf(v10[r], v11[r]));                           \
        }                                                                      \
    }                                                                          \
    float dd = fmaxf(lm0 - m0_, lm1 - m1_);                                    \
    if (__any(dd > 11.54f)) {               /* defer-max (log2 domain) */      \
        float lr0 = fmaxf(lm0, __shfl_xor(lm0, 16));                           \
        lr0 = fmaxf(lr0, __shfl_xor(lr0, 32));                                 \
        float lr1 = fmaxf(lm1, __shfl_xor(lm1, 16));                           \
        lr1 = fmaxf(lr1, __shfl_xor(lr1, 32));                                 \
        float mn0 = fmaxf(m0_, lr0), mn1 = fmaxf(m1_, lr1);                    \
        float al0 = __builtin_amdgcn_exp2f(m0_ - mn0);                         \
        float al1 = __builtin_amdgcn_exp2f(m1_ - mn1);                         \
        m0_ = mn0; m1_ = mn1;                                                  \
        lp0 *= al0; lp1 *= al1;                                                \
        for (int r = 0; r < 4; ++r) {                                          \
            float ar0 = __shfl(al0, quad * 4 + r);                             \
            float ar1 = __shfl(al1, quad * 4 + r);                             \
            for (int nt = 0; nt < 4; ++nt) {                                   \
                o0[nt][r] *= ar0;                                              \
                o1[nt][r] *= ar1;                                              \
            }                                                                  \
        }                                                                      \
    }                                                                          \
    for (int r = 0; r < 4; ++r) {                                              \
        v00[r] = __builtin_amdgcn_exp2f(v00[r] - m0_);                         \
        v01[r] = __builtin_amdgcn_exp2f(v01[r] - m0_);                         \
        v10[r] = __builtin_amdgcn_exp2f(v10[r] - m1_);                         \
        v11[r] = __builtin_amdgcn_exp2f(v11[r] - m1_);                         \
        lp0 += v00[r] + v01[r];                                                \
        lp1 += v10[r] + v11[r];                                                \
    }                                                                          \
    u32 fwa0[4], fwa1[4];                                                      \
    {                                                                          \
        u32 A0 = pkc(v00[0], v00[1]), A1 = pkc(v00[2], v00[3]);                \
        u32 B0 = pkc(v01[0], v01[1]), B1 = pkc(v01[2], v01[3]);                \
        u32 g0 = hi5 ? A0 : B0,  g1 = hi5 ? A1 : B1;                           \
        u32 r0 = __shfl_xor(g0, 32), r1 = __shfl_xor(g1, 32);                  \
        u32 P00 = hi5 ? r0 : A0,  P01 = hi5 ? r1 : A1;                         \
        u32 P10 = hi5 ? B0 : r0,  P11 = hi5 ? B1 : r1;                         \
        u32 h0 = hi4 ? P00 : P10, h1 = hi4 ? P01 : P11;                        \
        u32 u0 = __shfl_xor(h0, 16), u1 = __shfl_xor(h1, 16);                  \
        fwa0[0] = hi4 ? u0 : P00;  fwa0[1] = hi4 ? u1 : P01;                   \
        fwa0[2] = hi4 ? P10 : u0;  fwa0[3] = hi4 ? P11 : u1;                   \
    }                                                                          \
    {                                                                          \
        u32 A0 = pkc(v10[0], v10[1]), A1 = pkc(v10[2], v10[3]);                \
        u32 B0 = pkc(v11[0], v11[1]), B1 = pkc(v11[2], v11[3]);                \
        u32 g0 = hi5 ? A0 : B0,  g1 = hi5 ? A1 : B1;                           \
        u32 r0 = __shfl_xor(g0, 32), r1 = __shfl_xor(g1, 32);                  \
        u32 P00 = hi5 ? r0 : A0,  P01 = hi5 ? r1 : A1;                         \
        u32 P10 = hi5 ? B0 : r0,  P11 = hi5 ? B1 : r1;                         \
        u32 h0 = hi4 ? P00 : P10, h1 = hi4 ? P01 : P11;                        \
        u32 u0 = __shfl_xor(h0, 16), u1 = __shfl_xor(h1, 16);                  \
        fwa1[0] = hi4 ? u0 : P00;  fwa1[1] = hi4 ? u1 : P01;                   \
        fwa1[2] = hi4 ? P10 : u0;  fwa1[3] = hi4 ? P11 : u1;                   \
    }                                                                          \
    bf16x8 pf0, pf1;                                                           \
    __builtin_memcpy(&pf0, fwa0, 16);                                          \
    __builtin_memcpy(&pf1, fwa1, 16);                                          \
    o0[0] = FA_MFMA(pf0, V0, o0[0]);  o1[0] = FA_MFMA(pf1, V0, o1[0]);         \
    o0[1] = FA_MFMA(pf0, V1, o0[1]);  o1[1] = FA_MFMA(pf1, V1, o1[1]);         \
    o0[2] = FA_MFMA(pf0, V2, o0[2]);  o1[2] = FA_MFMA(pf1, V2, o1[2]);         \
    o0[3] = FA_MFMA(pf0, V3, o0[3]);  o1[3] = FA_MFMA(pf1, V3, o1[3]);         \
} while (0)

__global__ __launch_bounds__(128) void flash_attn(const u16* __restrict__ Qp,
                                                  const u16* __restrict__ Kp,
                                                  const u16* __restrict__ Vt,
                                                  u16* __restrict__ O) {
    __shared__ float osm[32][68];        // wave-1 partial o, +4 pad
    __shared__ float mMm[32], mLm[32];   // wave-1 m / l
    const int tid  = threadIdx.x;
    const int wave = tid >> 6, lane = tid & 63;
    const int quad = lane >> 4, col = lane & 15;
    const bool hi5 = lane >= 32;
    const bool hi4 = (lane & 16) != 0;
    const int bh = blockIdx.x;                 // XCD-pinned: lin%8 == bh%8
    const int b = bh >> 4, h = bh & 15;
    const int qt = 63 - blockIdx.y;            // heavy tiles first
    const int q0 = qt * 32;

    const u16* Qb = Qp + (size_t)bh * SEQ * 64;
    const u16* Kb = Kp + (size_t)bh * SEQ * 64;
    const u16* Vb = Vt + (size_t)bh * 64 * SEQ;

    // Q as B-operand for both halves (n=col -> query, k=quad*8+j)
    bf16x8 bq00 = ld_bf8(Qb + (size_t)(q0 + col) * 64 + quad * 8);
    bf16x8 bq01 = ld_bf8(Qb + (size_t)(q0 + col) * 64 + 32 + quad * 8);
    bf16x8 bq10 = ld_bf8(Qb + (size_t)(q0 + 16 + col) * 64 + quad * 8);
    bf16x8 bq11 = ld_bf8(Qb + (size_t)(q0 + 16 + col) * 64 + 32 + quad * 8);

    f32x4 zero = {0.f, 0.f, 0.f, 0.f};
    f32x4 o0[4] = {zero, zero, zero, zero};
    f32x4 o1[4] = {zero, zero, zero, zero};
    float m0_ = -1e30f, m1_ = -1e30f;
    float lp0 = 0.f, lp1 = 0.f;                // per-lane l partials

    const int nkt = qt + 1;                    // 32-key tiles (causal)
    const size_t koff = (size_t)col * 64 + quad * 8;   // lane offsets (elems)
    const size_t voff = (size_t)col * SEQ + quad * 8;

    int kt = wave;
    if (kt < nkt) {
        bf16x8 aK00, aK01, aK10, aK11, aV0, aV1, aV2, aV3;
        bf16x8 cK00, cK01, cK10, cK11, cV0, cV1, cV2, cV3;
        FA_LD(aK00, aK01, aK10, aK11, aV0, aV1, aV2, aV3, kt);
        FA_LD(cK00, cK01, cK10, cK11, cV0, cV1, cV2, cV3, kt + 2);
        while (true) {
            FA_TILE(aK00, aK01, aK10, aK11, aV0, aV1, aV2, aV3, kt);
            kt += 2; if (kt >= nkt) break;
            FA_LD(aK00, aK01, aK10, aK11, aV0, aV1, aV2, aV3, kt + 2);
            FA_TILE(cK00, cK01, cK10, cK11, cV0, cV1, cV2, cV3, kt);
            kt += 2; if (kt >= nkt) break;
            FA_LD(cK00, cK01, cK10, cK11, cV0, cV1, cV2, cV3, kt + 2);
        }
    }

    // ---- l totals (both waves)
    float lt0 = lp0;
    lt0 += __shfl_xor(lt0, 16); lt0 += __shfl_xor(lt0, 32);
    float lt1 = lp1;
    lt1 += __shfl_xor(lt1, 16); lt1 += __shfl_xor(lt1, 32);

    // ---- wave 1 publishes its partial; wave 0 merges after the barrier
    if (wave == 1) {
        if (quad == 0) {
            mMm[col] = m0_;      mLm[col] = lt0;
            mMm[16 + col] = m1_; mLm[16 + col] = lt1;
        }
        for (int nt = 0; nt < 4; ++nt)
            for (int r = 0; r < 4; ++r) {
                osm[quad * 4 + r][nt * 16 + col]      = o0[nt][r];
                osm[16 + quad * 4 + r][nt * 16 + col] = o1[nt][r];
            }
    }
    __syncthreads();

    if (wave == 0) {
        for (int r = 0; r < 4; ++r) {
            const int qr = quad * 4 + r;
            // half 0
            {
                float mw0 = __shfl(m0_, qr);
                float lw0 = __shfl(lt0, qr);
                float mw1 = mMm[qr], lw1 = mLm[qr];
                float M  = fmaxf(mw0, mw1);
                float e0 = __builtin_amdgcn_exp2f(mw0 - M);
                float e1 = __builtin_amdgcn_exp2f(mw1 - M);
                float inv = 1.f / (e0 * lw0 + e1 * lw1);
                for (int nt = 0; nt < 4; ++nt)
                    O[((size_t)b * SEQ + q0 + qr) * DM + h * 64 + nt * 16 + col] =
                        f2b((e0 * o0[nt][r] + e1 * osm[qr][nt * 16 + col]) * inv);
            }
            // half 1
            {
                float mw0 = __shfl(m1_, qr);
                float lw0 = __shfl(lt1, qr);
                float mw1 = mMm[16 + qr], lw1 = mLm[16 + qr];
                float M  = fmaxf(mw0, mw1);
                float e0 = __builtin_amdgcn_exp2f(mw0 - M);
                float e1 = __builtin_amdgcn_exp2f(mw1 - M);
                float inv = 1.f / (e0 * lw0 + e1 * lw1);
                for (int nt = 0; nt < 4; ++nt)
                    O[((size_t)b * SEQ + q0 + 16 + qr) * DM + h * 64 + nt * 16 + col] =
                        f2b((e0 * o1[nt][r] + e1 * osm[16 + qr][nt * 16 + col]) * inv);
            }
        }
    }
}

// ---------------------------------------------------------------------------
extern "C" void kernel_launch(void* const* d_in, const int* in_sizes, int n_in,
                              void* d_out, int out_size, void* d_ws, size_t ws_size,
                              hipStream_t stream) {
    const float* x    = (const float*)d_in[0];   // fp32 inputs (R3->R5 proven)
    const float* Wq   = (const float*)d_in[2];
    const float* Wk   = (const float*)d_in[3];
    const float* Wv   = (const float*)d_in[4];
    const float* Wo   = (const float*)d_in[5];
    const float* cosT = (const float*)d_in[6];
    const float* sinT = (const float*)d_in[7];
    float* out = (float*)d_out;                  // fp32 output (R8 proven)

    // Workspace: 16,777,216 u16 = 32 MiB (R8-proven safe size).
    u16* ws    = (u16*)d_ws;
    u16* qp    = ws;               // (bh,s,d)
    u16* kp    = ws + 4194304;
    u16* vt    = ws + 8388608;     // (bh,d,s); dead after flash
    u16* woT   = ws + 8388608;     // overlays vt, written after flash
    u16* wqkvT = ws + 12582912;    // dead after gemm_qkv
    u16* ao    = ws + 12582912;    // overlays wqkvT
    // bf16 copy of x lives in the OUTPUT buffer (8 of its 16 MiB): out is
    // dead until gemm_wo, which rewrites every element afterwards.
    u16* xb    = (u16*)out;

    dim3 blk(256);
    transpose_wqkv<<<dim3(16, 16, 3), blk, 0, stream>>>(Wq, Wk, Wv, wqkvT);
    cvt_x<<<dim3(2048), blk, 0, stream>>>(x, xb);
    gemm_qkv<<<dim3(32, 24), blk, 0, stream>>>(xb, wqkvT, qp, kp, vt);
    rope_qk<<<dim3(2048), blk, 0, stream>>>(qp, kp, cosT, sinT);
    flash_attn<<<dim3(NBH, 64), dim3(128), 0, stream>>>(qp, kp, vt, ao);
    transpose_wo<<<dim3(16, 16), blk, 0, stream>>>(Wo, woT);
    gemm_wo<<<dim3(32, 16), blk, 0, stream>>>(ao, woT, out);
}

// Round 9
// 224.024 us; speedup vs baseline: 1.0625x; 1.0429x over previous
//
#include <hip/hip_runtime.h>

typedef unsigned short u16;
typedef unsigned int   u32;
typedef __bf16  bf16x8 __attribute__((ext_vector_type(8)));
typedef float   f32x4  __attribute__((ext_vector_type(4)));
typedef u32     u32x4  __attribute__((ext_vector_type(4)));

#define SEQ    2048
#define HEADS  16
#define DM     1024
#define NBH    32      /* B*H */
#define NBS    4096    /* B*S */

// log2(e): flash softmax runs in exp2 domain; folded into Q in gemm epilogue.
#define LOG2E  1.4426950408889634f

__device__ __forceinline__ u16 f2b(float f) {
    u32 x;
    __builtin_memcpy(&x, &f, 4);
    return (u16)((x + 0x7fffu + ((x >> 16) & 1u)) >> 16);  // RNE
}

// Native-cast pack: compiler emits v_cvt_pk_bf16_f32 (RNE on gfx950).
__device__ __forceinline__ u32 pkc(float lo, float hi) {
    __bf16 a = (__bf16)lo, b = (__bf16)hi;
    u16 x, y;
    __builtin_memcpy(&x, &a, 2);
    __builtin_memcpy(&y, &b, 2);
    return (u32)x | ((u32)y << 16);
}

__device__ __forceinline__ bf16x8 ld_bf8(const u16* p) {
    return *(const bf16x8*)p;
}

// Async global->LDS, 16 B per lane. LDS dest must be linear (wave-uniform
// base + lane*16); any swizzle goes on the GLOBAL source address (T21).
__device__ __forceinline__ void gl_lds16(const u16* g, __bf16* l) {
    __builtin_amdgcn_global_load_lds(
        (__attribute__((address_space(1))) void*)g,
        (__attribute__((address_space(3))) void*)l,
        16, 0, 0);
}

// ---------------------------------------------------------------------------
// Transpose + fp32->bf16 of W_Q/W_K/W_V: (k,n) -> WqkvT[z*1024 + n][k].
// ---------------------------------------------------------------------------
__global__ __launch_bounds__(256) void transpose_wqkv(const float* __restrict__ Wq,
                                                      const float* __restrict__ Wk,
                                                      const float* __restrict__ Wv,
                                                      u16* __restrict__ WqkvT) {
    __shared__ u16 tile[64][65];
    const int z  = blockIdx.z;
    const float* src = (z == 0) ? Wq : (z == 1) ? Wk : Wv;
    const int k0 = blockIdx.x * 64, n0 = blockIdx.y * 64;
    const int tid = threadIdx.x;
    for (int i = 0; i < 16; ++i) {
        int e = i * 256 + tid;
        int r = e >> 6, c = e & 63;
        tile[r][c] = f2b(src[(size_t)(k0 + r) * DM + n0 + c]);
    }
    __syncthreads();
    u16* dst = WqkvT + (size_t)z * DM * DM;
    for (int i = 0; i < 16; ++i) {
        int e = i * 256 + tid;
        int r = e >> 6, c = e & 63;
        dst[(size_t)(n0 + r) * DM + k0 + c] = tile[c][r];
    }
}

// W_O (k,n) fp32 -> WoT[n][k] bf16. Launched AFTER flash (overlays dead vt).
__global__ __launch_bounds__(256) void transpose_wo(const float* __restrict__ Wo,
                                                    u16* __restrict__ WoT) {
    __shared__ u16 tile[64][65];
    const int k0 = blockIdx.x * 64, n0 = blockIdx.y * 64;
    const int tid = threadIdx.x;
    for (int i = 0; i < 16; ++i) {
        int e = i * 256 + tid;
        int r = e >> 6, c = e & 63;
        tile[r][c] = f2b(Wo[(size_t)(k0 + r) * DM + n0 + c]);
    }
    __syncthreads();
    for (int i = 0; i < 16; ++i) {
        int e = i * 256 + tid;
        int r = e >> 6, c = e & 63;
        WoT[(size_t)(n0 + r) * DM + k0 + c] = tile[c][r];
    }
}

// ---------------------------------------------------------------------------
// x fp32 -> bf16, 8 elems/thread. Output xb lives in the (dead until gemm_wo)
// fp32 output buffer: gemm_wo rewrites every byte of `out` afterwards.
// ---------------------------------------------------------------------------
__global__ __launch_bounds__(256) void cvt_x(const float* __restrict__ x,
                                             u16* __restrict__ xb) {
    int t = blockIdx.x * 256 + threadIdx.x;     // [0, 524288)
    const float* p = x + (size_t)t * 8;
    f32x4 a = *(const f32x4*)p;
    f32x4 b = *(const f32x4*)(p + 4);
    u32x4 v;
    v[0] = pkc(a[0], a[1]);
    v[1] = pkc(a[2], a[3]);
    v[2] = pkc(b[0], b[1]);
    v[3] = pkc(b[2], b[3]);
    *(u32x4*)(xb + (size_t)t * 8) = v;
}

// ---------------------------------------------------------------------------
// Fused QKV GEMM + RoPE: xb(4096x1024 bf16) x WqkvT(3072x1024 bf16)^T.
// 128x128 tile, BK=64, both operands via global_load_lds. The epilogue for
// Q/K blocks (blockIdx.y uniform) applies RoPE IN F32 before rounding:
// partner element lives at lane^1 (d and d^1 share nt, differ in col bit0),
// so rotation = 1 shfl_xor + select + 2 fma per element. Q additionally gets
// 0.125*log2e (flash softmax runs in exp2 domain). Kills the rope_qk kernel
// and one full 32 MB Q/K memory round trip, and removes double rounding.
// Scatters to Qp (bh,s,d), Kp (bh,s,d), Vt (bh,d,s).
// ---------------------------------------------------------------------------
__global__ __launch_bounds__(256) void gemm_qkv(const u16* __restrict__ Ab,
                                                const u16* __restrict__ Bt,
                                                u16* __restrict__ Qp,
                                                u16* __restrict__ Kp,
                                                u16* __restrict__ Vt,
                                                const float* __restrict__ cosT,
                                                const float* __restrict__ sinT) {
    __shared__ __attribute__((aligned(16))) __bf16 As[128 * 64];
    __shared__ __attribute__((aligned(16))) __bf16 Bs[128 * 64];
    const int tid  = threadIdx.x;
    const int wave = tid >> 6, lane = tid & 63;
    const int quad = lane >> 4, col = lane & 15;
    const int wm = wave >> 1, wn = wave & 1;
    const int m0 = blockIdx.x * 128, n0 = blockIdx.y * 128;
    const int srow = tid >> 3;                  // 0..31
    const int aslot = (((tid & 7) ^ (srow & 7)) << 3);  // swizzled slot (elems)
    const int c7 = col & 7;

    f32x4 zero = {0.f, 0.f, 0.f, 0.f};
    f32x4 acc[4][4];
    for (int i = 0; i < 4; ++i)
        for (int j = 0; j < 4; ++j) acc[i][j] = zero;

    for (int k0 = 0; k0 < DM; k0 += 64) {
        __syncthreads();
#pragma unroll
        for (int p = 0; p < 4; ++p)
            gl_lds16(Ab + (size_t)(m0 + p * 32 + srow) * DM + k0 + aslot,
                     &As[p * 2048 + tid * 8]);
#pragma unroll
        for (int p = 0; p < 4; ++p)
            gl_lds16(Bt + (size_t)(n0 + p * 32 + srow) * DM + k0 + aslot,
                     &Bs[p * 2048 + tid * 8]);
        __syncthreads();
#pragma unroll
        for (int ks = 0; ks < 2; ++ks) {
            const int rsl = ((((ks << 2) | quad) ^ c7) << 3);
            bf16x8 af[4], bfr[4];
#pragma unroll
            for (int mt = 0; mt < 4; ++mt)
                af[mt] = *(const bf16x8*)&As[(wm * 64 + mt * 16 + col) * 64 + rsl];
#pragma unroll
            for (int nt = 0; nt < 4; ++nt)
                bfr[nt] = *(const bf16x8*)&Bs[(wn * 64 + nt * 16 + col) * 64 + rsl];
#pragma unroll
            for (int mt = 0; mt < 4; ++mt)
#pragma unroll
                for (int nt = 0; nt < 4; ++nt)
                    acc[mt][nt] = __builtin_amdgcn_mfma_f32_16x16x32_bf16(
                        af[mt], bfr[nt], acc[mt][nt], 0, 0, 0);
        }
    }

    // C/D: col = lane&15, row = quad*4 + reg (m89-verified).
    const int which = blockIdx.y >> 3;          // block-uniform: 0=Q 1=K 2=V
    if (which < 2) {
        u16* dst = (which == 0) ? Qp : Kp;
        const float sc = (which == 0) ? 0.125f * LOG2E : 1.f;
        for (int mt = 0; mt < 4; ++mt)
            for (int nt = 0; nt < 4; ++nt) {
                const int d = nt * 16 + col;    // = cc & 63
                const int p = d >> 1;
                const int h = ((n0 + wn * 64 + nt * 16 + col) & 1023) >> 6;
                for (int r = 0; r < 4; ++r) {
                    int row = m0 + wm * 64 + mt * 16 + quad * 4 + r;
                    int s = row & (SEQ - 1);
                    int bb = row >> 11;
                    float c  = cosT[s * 32 + p];
                    float sn = sinT[s * 32 + p];
                    float self = acc[mt][nt][r];
                    float part = __shfl_xor(self, 1);
                    // even d: c*self - sn*part ; odd d: sn*part + c*self
                    float out = (col & 1) ? (sn * part + c * self)
                                          : (c * self - sn * part);
                    out *= sc;
                    dst[(((size_t)(bb * HEADS + h)) * SEQ + s) * 64 + d] = f2b(out);
                }
            }
    } else {
        for (int mt = 0; mt < 4; ++mt)
            for (int nt = 0; nt < 4; ++nt) {
                int c1 = (n0 + wn * 64 + nt * 16 + col) & 1023;
                int h = c1 >> 6, d = c1 & 63;
                for (int r = 0; r < 4; ++r) {
                    int row = m0 + wm * 64 + mt * 16 + quad * 4 + r;
                    int bb = row >> 11, s = row & (SEQ - 1);
                    Vt[(((size_t)(bb * HEADS + h)) * 64 + d) * SEQ + s] =
                        f2b(acc[mt][nt][r]);
                }
            }
    }
}

// ---------------------------------------------------------------------------
// Output GEMM: ao(4096x1024 bf16) x WoT(1024x1024 bf16)^T -> out FP32.
// 128x64 tile -> grid (32,16) = 512 blocks = 2 blocks/CU.
// ---------------------------------------------------------------------------
__global__ __launch_bounds__(256) void gemm_wo(const u16* __restrict__ A,
                                               const u16* __restrict__ Bt,
                                               float* __restrict__ C) {
    __shared__ __attribute__((aligned(16))) __bf16 As[128 * 64];
    __shared__ __attribute__((aligned(16))) __bf16 Bs[64 * 64];
    const int tid  = threadIdx.x;
    const int wave = tid >> 6, lane = tid & 63;
    const int quad = lane >> 4, col = lane & 15;
    const int m0 = blockIdx.x * 128, n0 = blockIdx.y * 64;
    const int srow = tid >> 3;
    const int aslot = (((tid & 7) ^ (srow & 7)) << 3);
    const int c7 = col & 7;

    f32x4 zero = {0.f, 0.f, 0.f, 0.f};
    f32x4 acc[2][4];
    for (int i = 0; i < 2; ++i)
        for (int j = 0; j < 4; ++j) acc[i][j] = zero;

    for (int k0 = 0; k0 < DM; k0 += 64) {
        __syncthreads();
#pragma unroll
        for (int p = 0; p < 4; ++p)
            gl_lds16(A + (size_t)(m0 + p * 32 + srow) * DM + k0 + aslot,
                     &As[p * 2048 + tid * 8]);
#pragma unroll
        for (int p = 0; p < 2; ++p)
            gl_lds16(Bt + (size_t)(n0 + p * 32 + srow) * DM + k0 + aslot,
                     &Bs[p * 2048 + tid * 8]);
        __syncthreads();
#pragma unroll
        for (int ks = 0; ks < 2; ++ks) {
            const int rsl = ((((ks << 2) | quad) ^ c7) << 3);
            bf16x8 af[2], bfr[4];
#pragma unroll
            for (int mt = 0; mt < 2; ++mt)
                af[mt] = *(const bf16x8*)&As[(wave * 32 + mt * 16 + col) * 64 + rsl];
#pragma unroll
            for (int nt = 0; nt < 4; ++nt)
                bfr[nt] = *(const bf16x8*)&Bs[(nt * 16 + col) * 64 + rsl];
#pragma unroll
            for (int mt = 0; mt < 2; ++mt)
#pragma unroll
                for (int nt = 0; nt < 4; ++nt)
                    acc[mt][nt] = __builtin_amdgcn_mfma_f32_16x16x32_bf16(
                        af[mt], bfr[nt], acc[mt][nt], 0, 0, 0);
        }
    }

    for (int mt = 0; mt < 2; ++mt)
        for (int nt = 0; nt < 4; ++nt)
            for (int r = 0; r < 4; ++r) {
                int row = m0 + wave * 32 + mt * 16 + quad * 4 + r;
                int cc  = n0 + nt * 16 + col;
                C[(size_t)row * DM + cc] = acc[mt][nt][r];
            }
}

// ---------------------------------------------------------------------------
// Causal flash attention — VERBATIM restore of the round-5-proven core
// (benched 79.5 us, passed): split-key (4 waves) x dual 16-query halves,
// XCD-pinned bh, K AND V prefetched one full iteration ahead (clamped),
// exp2-domain softmax (scale folded into Q upstream), shuffle-butterfly
// P-transpose, defer-max (threshold 8*log2e = 11.54), per-lane l partials,
// exp-weighted LDS merge of the 4 wave partials.
// R8's static-shift rewrite produced an o/l key-set mismatch (absmax 7.7e4
// ~ 2^16 x O(1)); it is reverted wholesale — proven bits only.
// Qp,Kp: (bh,s,64)  Vt: (bh,64,s)  O: (b, s, h*64+d) bf16.
// ---------------------------------------------------------------------------
__global__ __launch_bounds__(256, 3) void flash_attn(const u16* __restrict__ Qp,
                                                     const u16* __restrict__ Kp,
                                                     const u16* __restrict__ Vt,
                                                     u16* __restrict__ O) {
    __shared__ float os[4][32][68];       // [wave][query][d], +4 pad
    __shared__ float mM[4][32];
    __shared__ float mL[4][32];
    const int tid  = threadIdx.x;
    const int wave = tid >> 6, lane = tid & 63;
    const int quad = lane >> 4, col = lane & 15;
    const bool hi5 = lane >= 32;
    const bool hi4 = (lane & 16) != 0;
    const int bh = blockIdx.x;                 // XCD-pinned: lin%8 == bh%8
    const int b = bh >> 4, h = bh & 15;
    const int qt = 63 - blockIdx.y;            // heavy tiles first
    const int q0 = qt * 32;

    const u16* Qb = Qp + (size_t)bh * SEQ * 64;
    const u16* Kb = Kp + (size_t)bh * SEQ * 64;
    const u16* Vb = Vt + (size_t)bh * 64 * SEQ;

    // Q as B-operand for both halves (n=col -> query, k=quad*8+j)
    bf16x8 bq00 = ld_bf8(Qb + (size_t)(q0 + col) * 64 + quad * 8);
    bf16x8 bq01 = ld_bf8(Qb + (size_t)(q0 + col) * 64 + 32 + quad * 8);
    bf16x8 bq10 = ld_bf8(Qb + (size_t)(q0 + 16 + col) * 64 + quad * 8);
    bf16x8 bq11 = ld_bf8(Qb + (size_t)(q0 + 16 + col) * 64 + 32 + quad * 8);

    f32x4 zero = {0.f, 0.f, 0.f, 0.f};
    f32x4 o0[4] = {zero, zero, zero, zero};
    f32x4 o1[4] = {zero, zero, zero, zero};
    float m0_ = -1e30f, m1_ = -1e30f;
    float lp0 = 0.f, lp1 = 0.f;                // per-lane l partials

    const int nkt = qt + 1;                    // 32-key tiles (causal)
    int kt = wave;
    bf16x8 ck00, ck01, ck10, ck11, cv0, cv1, cv2, cv3;
    if (kt < nkt) {
        const int kb = kt << 5;
        ck00 = ld_bf8(Kb + (size_t)(kb + col) * 64 + quad * 8);
        ck01 = ld_bf8(Kb + (size_t)(kb + col) * 64 + 32 + quad * 8);
        ck10 = ld_bf8(Kb + (size_t)(kb + 16 + col) * 64 + quad * 8);
        ck11 = ld_bf8(Kb + (size_t)(kb + 16 + col) * 64 + 32 + quad * 8);
        cv0  = ld_bf8(Vb + (size_t)(0 * 16 + col) * SEQ + kb + quad * 8);
        cv1  = ld_bf8(Vb + (size_t)(1 * 16 + col) * SEQ + kb + quad * 8);
        cv2  = ld_bf8(Vb + (size_t)(2 * 16 + col) * SEQ + kb + quad * 8);
        cv3  = ld_bf8(Vb + (size_t)(3 * 16 + col) * SEQ + kb + quad * 8);
    }

    for (; kt < nkt; kt += 4) {
        // NEXT K and V tiles, unconditional (clamped on last iteration)
        int kn = kt + 4; if (kn >= nkt) kn = kt;
        const int kb2 = kn << 5;
        bf16x8 nk00 = ld_bf8(Kb + (size_t)(kb2 + col) * 64 + quad * 8);
        bf16x8 nk01 = ld_bf8(Kb + (size_t)(kb2 + col) * 64 + 32 + quad * 8);
        bf16x8 nk10 = ld_bf8(Kb + (size_t)(kb2 + 16 + col) * 64 + quad * 8);
        bf16x8 nk11 = ld_bf8(Kb + (size_t)(kb2 + 16 + col) * 64 + 32 + quad * 8);
        bf16x8 nv0  = ld_bf8(Vb + (size_t)(0 * 16 + col) * SEQ + kb2 + quad * 8);
        bf16x8 nv1  = ld_bf8(Vb + (size_t)(1 * 16 + col) * SEQ + kb2 + quad * 8);
        bf16x8 nv2  = ld_bf8(Vb + (size_t)(2 * 16 + col) * SEQ + kb2 + quad * 8);
        bf16x8 nv3  = ld_bf8(Vb + (size_t)(3 * 16 + col) * SEQ + kb2 + quad * 8);

        // S^T (log2-domain): two independent chains, 8 MFMA
        f32x4 s00 = zero, s01 = zero, s10 = zero, s11 = zero;
        s00 = __builtin_amdgcn_mfma_f32_16x16x32_bf16(ck00, bq00, s00, 0, 0, 0);
        s10 = __builtin_amdgcn_mfma_f32_16x16x32_bf16(ck00, bq10, s10, 0, 0, 0);
        s00 = __builtin_amdgcn_mfma_f32_16x16x32_bf16(ck01, bq01, s00, 0, 0, 0);
        s10 = __builtin_amdgcn_mfma_f32_16x16x32_bf16(ck01, bq11, s10, 0, 0, 0);
        s01 = __builtin_amdgcn_mfma_f32_16x16x32_bf16(ck10, bq00, s01, 0, 0, 0);
        s11 = __builtin_amdgcn_mfma_f32_16x16x32_bf16(ck10, bq10, s11, 0, 0, 0);
        s01 = __builtin_amdgcn_mfma_f32_16x16x32_bf16(ck11, bq01, s01, 0, 0, 0);
        s11 = __builtin_amdgcn_mfma_f32_16x16x32_bf16(ck11, bq11, s11, 0, 0, 0);

        float v00[4], v01[4], v10[4], v11[4];
        float lm0 = -1e30f, lm1 = -1e30f;
        if (kt == qt) {                         // diagonal tile (wave-uniform)
            for (int r = 0; r < 4; ++r) {
                int krel = quad * 4 + r;
                float a0 = (krel > col) ? -1e30f : s00[r];
                float b0 = -1e30f;              // keys+16 > all half0 queries
                float a1 = s10[r];
                float b1 = (krel > col) ? -1e30f : s11[r];
                v00[r] = a0; v01[r] = b0; v10[r] = a1; v11[r] = b1;
                lm0 = fmaxf(lm0, fmaxf(a0, b0));
                lm1 = fmaxf(lm1, fmaxf(a1, b1));
            }
        } else {
            for (int r = 0; r < 4; ++r) {
                v00[r] = s00[r]; v01[r] = s01[r];
                v10[r] = s10[r]; v11[r] = s11[r];
                lm0 = fmaxf(lm0, fmaxf(v00[r], v01[r]));
                lm1 = fmaxf(lm1, fmaxf(v10[r], v11[r]));
            }
        }

        // Defer-max (log2 domain: 8*log2e = 11.54)
        float dd = fmaxf(lm0 - m0_, lm1 - m1_);
        if (__any(dd > 11.54f)) {
            float lr0 = fmaxf(lm0, __shfl_xor(lm0, 16));
            lr0 = fmaxf(lr0, __shfl_xor(lr0, 32));
            float lr1 = fmaxf(lm1, __shfl_xor(lm1, 16));
            lr1 = fmaxf(lr1, __shfl_xor(lr1, 32));
            float mn0 = fmaxf(m0_, lr0), mn1 = fmaxf(m1_, lr1);
            float al0 = __builtin_amdgcn_exp2f(m0_ - mn0);
            float al1 = __builtin_amdgcn_exp2f(m1_ - mn1);
            m0_ = mn0; m1_ = mn1;
            lp0 *= al0; lp1 *= al1;
            for (int r = 0; r < 4; ++r) {
                float ar0 = __shfl(al0, quad * 4 + r);
                float ar1 = __shfl(al1, quad * 4 + r);
                for (int nt = 0; nt < 4; ++nt) {
                    o0[nt][r] *= ar0;
                    o1[nt][r] *= ar1;
                }
            }
        }

        for (int r = 0; r < 4; ++r) {
            v00[r] = __builtin_amdgcn_exp2f(v00[r] - m0_);
            v01[r] = __builtin_amdgcn_exp2f(v01[r] - m0_);
            v10[r] = __builtin_amdgcn_exp2f(v10[r] - m1_);
            v11[r] = __builtin_amdgcn_exp2f(v11[r] - m1_);
            lp0 += v00[r] + v01[r];
            lp1 += v10[r] + v11[r];
        }

        // P^T(C-layout) -> A-fragment: 2-stage shuffle butterfly, per half.
        u32 fwa0[4], fwa1[4];
        {
            u32 A0 = pkc(v00[0], v00[1]), A1 = pkc(v00[2], v00[3]);
            u32 B0 = pkc(v01[0], v01[1]), B1 = pkc(v01[2], v01[3]);
            u32 g0 = hi5 ? A0 : B0,  g1 = hi5 ? A1 : B1;
            u32 r0 = __shfl_xor(g0, 32), r1 = __shfl_xor(g1, 32);
            u32 P00 = hi5 ? r0 : A0,  P01 = hi5 ? r1 : A1;
            u32 P10 = hi5 ? B0 : r0,  P11 = hi5 ? B1 : r1;
            u32 h0 = hi4 ? P00 : P10, h1 = hi4 ? P01 : P11;
            u32 u0 = __shfl_xor(h0, 16), u1 = __shfl_xor(h1, 16);
            fwa0[0] = hi4 ? u0 : P00;  fwa0[1] = hi4 ? u1 : P01;
            fwa0[2] = hi4 ? P10 : u0;  fwa0[3] = hi4 ? P11 : u1;
        }
        {
            u32 A0 = pkc(v10[0], v10[1]), A1 = pkc(v10[2], v10[3]);
            u32 B0 = pkc(v11[0], v11[1]), B1 = pkc(v11[2], v11[3]);
            u32 g0 = hi5 ? A0 : B0,  g1 = hi5 ? A1 : B1;
            u32 r0 = __shfl_xor(g0, 32), r1 = __shfl_xor(g1, 32);
            u32 P00 = hi5 ? r0 : A0,  P01 = hi5 ? r1 : A1;
            u32 P10 = hi5 ? B0 : r0,  P11 = hi5 ? B1 : r1;
            u32 h0 = hi4 ? P00 : P10, h1 = hi4 ? P01 : P11;
            u32 u0 = __shfl_xor(h0, 16), u1 = __shfl_xor(h1, 16);
            fwa1[0] = hi4 ? u0 : P00;  fwa1[1] = hi4 ? u1 : P01;
            fwa1[2] = hi4 ? P10 : u0;  fwa1[3] = hi4 ? P11 : u1;
        }
        bf16x8 pf0, pf1;
        __builtin_memcpy(&pf0, fwa0, 16);
        __builtin_memcpy(&pf1, fwa1, 16);

        // PV: 8 MFMA, independent across halves and nt
        o0[0] = __builtin_amdgcn_mfma_f32_16x16x32_bf16(pf0, cv0, o0[0], 0, 0, 0);
        o1[0] = __builtin_amdgcn_mfma_f32_16x16x32_bf16(pf1, cv0, o1[0], 0, 0, 0);
        o0[1] = __builtin_amdgcn_mfma_f32_16x16x32_bf16(pf0, cv1, o0[1], 0, 0, 0);
        o1[1] = __builtin_amdgcn_mfma_f32_16x16x32_bf16(pf1, cv1, o1[1], 0, 0, 0);
        o0[2] = __builtin_amdgcn_mfma_f32_16x16x32_bf16(pf0, cv2, o0[2], 0, 0, 0);
        o1[2] = __builtin_amdgcn_mfma_f32_16x16x32_bf16(pf1, cv2, o1[2], 0, 0, 0);
        o0[3] = __builtin_amdgcn_mfma_f32_16x16x32_bf16(pf0, cv3, o0[3], 0, 0, 0);
        o1[3] = __builtin_amdgcn_mfma_f32_16x16x32_bf16(pf1, cv3, o1[3], 0, 0, 0);

        ck00 = nk00; ck01 = nk01; ck10 = nk10; ck11 = nk11;
        cv0 = nv0; cv1 = nv1; cv2 = nv2; cv3 = nv3;
    }

    // ---- publish wave partials
    float lt0 = lp0;
    lt0 += __shfl_xor(lt0, 16); lt0 += __shfl_xor(lt0, 32);
    float lt1 = lp1;
    lt1 += __shfl_xor(lt1, 16); lt1 += __shfl_xor(lt1, 32);
    if (quad == 0) {
        mM[wave][col] = m0_;      mL[wave][col] = lt0;
        mM[wave][16 + col] = m1_; mL[wave][16 + col] = lt1;
    }
    for (int nt = 0; nt < 4; ++nt)
        for (int r = 0; r < 4; ++r) {
            os[wave][quad * 4 + r][nt * 16 + col]      = o0[nt][r];
            os[wave][16 + quad * 4 + r][nt * 16 + col] = o1[nt][r];
        }
    __syncthreads();

    // ---- merge 4 wave-partials: thread t -> query t>>3, d0 = (t&7)*8
    {
        const int q  = tid >> 3;
        const int d0 = (tid & 7) * 8;
        float M = fmaxf(fmaxf(mM[0][q], mM[1][q]), fmaxf(mM[2][q], mM[3][q]));
        float L = 0.f;
        f32x4 a0 = {0.f, 0.f, 0.f, 0.f}, a1 = {0.f, 0.f, 0.f, 0.f};
        for (int w = 0; w < 4; ++w) {
            float e = __builtin_amdgcn_exp2f(mM[w][q] - M);  // 0 for idle waves
            L += e * mL[w][q];
            f32x4 p0 = *(const f32x4*)&os[w][q][d0];
            f32x4 p1 = *(const f32x4*)&os[w][q][d0 + 4];
            for (int j = 0; j < 4; ++j) { a0[j] += e * p0[j]; a1[j] += e * p1[j]; }
        }
        float inv = 1.f / L;
        u32x4 val;
        val[0] = pkc(a0[0] * inv, a0[1] * inv);
        val[1] = pkc(a0[2] * inv, a0[3] * inv);
        val[2] = pkc(a1[0] * inv, a1[1] * inv);
        val[3] = pkc(a1[2] * inv, a1[3] * inv);
        *(u32x4*)&O[((size_t)b * SEQ + q0 + q) * DM + h * 64 + d0] = val;
    }
}

// ---------------------------------------------------------------------------
extern "C" void kernel_launch(void* const* d_in, const int* in_sizes, int n_in,
                              void* d_out, int out_size, void* d_ws, size_t ws_size,
                              hipStream_t stream) {
    const float* x    = (const float*)d_in[0];   // fp32 inputs (R3->R5 proven)
    const float* Wq   = (const float*)d_in[2];
    const float* Wk   = (const float*)d_in[3];
    const float* Wv   = (const float*)d_in[4];
    const float* Wo   = (const float*)d_in[5];
    const float* cosT = (const float*)d_in[6];
    const float* sinT = (const float*)d_in[7];
    float* out = (float*)d_out;                  // fp32 output (R8 proven)

    // Workspace: 16,777,216 u16 = 32 MiB (R8-proven safe size).
    u16* ws    = (u16*)d_ws;
    u16* qp    = ws;               // (bh,s,d)
    u16* kp    = ws + 4194304;
    u16* vt    = ws + 8388608;     // (bh,d,s); dead after flash
    u16* woT   = ws + 8388608;     // overlays vt, written after flash
    u16* wqkvT = ws + 12582912;    // dead after gemm_qkv
    u16* ao    = ws + 12582912;    // overlays wqkvT
    // bf16 copy of x lives in the OUTPUT buffer (8 of its 16 MiB): out is
    // dead until gemm_wo, which rewrites every element afterwards.
    u16* xb    = (u16*)out;

    dim3 blk(256);
    transpose_wqkv<<<dim3(16, 16, 3), blk, 0, stream>>>(Wq, Wk, Wv, wqkvT);
    cvt_x<<<dim3(2048), blk, 0, stream>>>(x, xb);
    gemm_qkv<<<dim3(32, 24), blk, 0, stream>>>(xb, wqkvT, qp, kp, vt, cosT, sinT);
    flash_attn<<<dim3(NBH, 64), blk, 0, stream>>>(qp, kp, vt, ao);
    transpose_wo<<<dim3(16, 16), blk, 0, stream>>>(Wo, woT);
    gemm_wo<<<dim3(32, 16), blk, 0, stream>>>(ao, woT, out);
}